// Round 1
// baseline (142.224 us; speedup 1.0000x reference)
//
#include <hip/hip_runtime.h>
#include <hip/hip_bf16.h>

// Problem constants
#define BPn   2048      // B*P
#define NEn   400
#define HIDn  128
#define RTOT  (BPn*NEn) // 819200
#define TILE_R 128

typedef __attribute__((ext_vector_type(8)))  short  short8;
typedef __attribute__((ext_vector_type(16))) float  f32x16;
typedef __attribute__((ext_vector_type(4)))  float  f32x4;

__device__ __forceinline__ unsigned short bf16u(float x) {
  unsigned int b = __builtin_bit_cast(unsigned int, x);
  b += 0x7FFFu + ((b >> 16) & 1u);
  return (unsigned short)(b >> 16);
}

__device__ __forceinline__ float silu_f(float x) {
  return x / (1.0f + __expf(-x));
}

// ---------------- prep: hp[2048][128] and he[400][128] (f32) ----------------
__global__ void prep_emb(const int* __restrict__ z_j, const int* __restrict__ z_k,
                         const float* __restrict__ e_feat, const float* __restrict__ z_emb,
                         const float* __restrict__ W1, const float* __restrict__ b1,
                         float* __restrict__ hp, float* __restrict__ he)
{
  const int t = threadIdx.x;           // 0..127
  const int bidx = blockIdx.x;
  if (bidx < BPn) {
    const int zj = z_j[bidx], zk = z_k[bidx];
    const float* ej = z_emb + zj * 64;
    const float* ek = z_emb + zk * 64;
    float acc = b1[t];
    #pragma unroll 8
    for (int k = 0; k < 64; ++k) acc += ej[k] * W1[k * 128 + t];
    #pragma unroll 8
    for (int k = 0; k < 64; ++k) acc += ek[k] * W1[(64 + k) * 128 + t];
    hp[bidx * 128 + t] = acc;
  } else {
    const int e = bidx - BPn;          // 0..399
    float acc = 0.0f;
    #pragma unroll 8
    for (int k = 0; k < 32; ++k) acc += e_feat[e * 32 + k] * W1[(128 + k) * 128 + t];
    he[e * 128 + t] = acc;
  }
}

// ---------------- prep: weights to bf16, pre-inverse-swizzled ----------------
// w2t byte layout: value W2[k][n] stored at byte ((n*256 + 2k) ^ ((n&7)<<4))
// w3f layout: [ks][lane][j] with B[k=ks*32+(lane>>4)*8+j][col=lane&15]
__global__ void prep_w(const float* __restrict__ W2, const float* __restrict__ W3,
                       unsigned short* __restrict__ w2t, unsigned short* __restrict__ w3f)
{
  const int idx = blockIdx.x * 256 + threadIdx.x;
  if (idx < 16384) {
    const int n = idx >> 7, k = idx & 127;
    const unsigned short v = bf16u(W2[k * 128 + n]);
    const int byte = (n * 256 + k * 2) ^ ((n & 7) << 4);
    w2t[byte >> 1] = v;
  }
  if (idx < 2048) {
    const int ks = idx >> 9;
    const int l  = (idx >> 3) & 63;
    const int j  = idx & 7;
    const int k  = ks * 32 + ((l >> 4) & 3) * 8 + j;
    const int col = l & 15;
    w3f[idx] = bf16u(W3[k * 16 + col]);
  }
}

// ---------------- fused main ----------------
__global__ __launch_bounds__(256, 2)
void fused_main(const float* __restrict__ hp, const float* __restrict__ he,
                const unsigned short* __restrict__ w2t, const unsigned short* __restrict__ w3f,
                const float* __restrict__ b2, const float* __restrict__ b3,
                float* __restrict__ out)
{
  __shared__ __align__(16) unsigned short ldsA[16384]; // 32KB: A (silu layer1), then H2
  __shared__ __align__(16) unsigned short ldsB[16384]; // 32KB: W2^T bf16 swizzled
  const int t    = threadIdx.x;
  const int lane = t & 63;
  const int wid  = t >> 6;
  const int r0   = blockIdx.x * TILE_R;

  // ---- stage W2T (already swizzled in ws): linear 32KB copy ----
  {
    const uint4* src = (const uint4*)w2t;
    uint4* dst = (uint4*)ldsB;
    #pragma unroll
    for (int i = 0; i < 8; ++i) dst[t + i * 256] = src[t + i * 256];
  }

  // ---- build A = bf16(silu(hp + he)) into ldsA, swizzled [row][k] ----
  #pragma unroll
  for (int i = 0; i < 8; ++i) {
    const int q   = t + i * 256;          // 0..2047 octet index
    const int row = q >> 4;               // 0..127
    const int k8  = (q & 15) << 3;        // 0,8,...,120
    const int rg  = r0 + row;
    const unsigned int bp = (unsigned int)(((unsigned long long)rg * 2748779070ull) >> 40); // rg/400 exact
    const unsigned int e  = (unsigned int)rg - bp * 400u;
    const float4* hpv = (const float4*)(hp + bp * 128 + k8);
    const float4* hev = (const float4*)(he + e  * 128 + k8);
    const float4 h0 = hpv[0], h1 = hpv[1];
    const float4 g0 = hev[0], g1 = hev[1];
    float v[8] = { h0.x + g0.x, h0.y + g0.y, h0.z + g0.z, h0.w + g0.w,
                   h1.x + g1.x, h1.y + g1.y, h1.z + g1.z, h1.w + g1.w };
    short8 av;
    #pragma unroll
    for (int j = 0; j < 8; ++j) av[j] = (short)bf16u(silu_f(v[j]));
    const int byte = (row * 256 + k8 * 2) ^ ((row & 7) << 4);
    *(short8*)((char*)ldsA + byte) = av;
  }
  __syncthreads();

  // ---- GEMM1: (128 x 128) @ W2 -> acc, 32x32x16 bf16 MFMA ----
  const int wm = wid >> 1, wn = wid & 1;   // 2x2 wave grid, 64x64 wave tile
  const int c  = lane & 31, hi = lane >> 5;
  f32x16 acc[2][2] = {};

  const int rowA = wm * 64 + c;
  const int colB = wn * 64 + c;
  const int swzA = (rowA & 7) << 4;        // rows r and r+32 share (r&7)
  const int swzB = (colB & 7) << 4;
  #pragma unroll
  for (int ks = 0; ks < 8; ++ks) {
    const int kb2 = (ks * 16 + hi * 8) * 2;
    short8 a0 = *(const short8*)((const char*)ldsA + (( rowA       * 256 + kb2) ^ swzA));
    short8 a1 = *(const short8*)((const char*)ldsA + (((rowA + 32) * 256 + kb2) ^ swzA));
    short8 b0 = *(const short8*)((const char*)ldsB + (( colB       * 256 + kb2) ^ swzB));
    short8 b1 = *(const short8*)((const char*)ldsB + (((colB + 32) * 256 + kb2) ^ swzB));
    acc[0][0] = __builtin_amdgcn_mfma_f32_32x32x16_bf16(a0, b0, acc[0][0], 0, 0, 0);
    acc[0][1] = __builtin_amdgcn_mfma_f32_32x32x16_bf16(a0, b1, acc[0][1], 0, 0, 0);
    acc[1][0] = __builtin_amdgcn_mfma_f32_32x32x16_bf16(a1, b0, acc[1][0], 0, 0, 0);
    acc[1][1] = __builtin_amdgcn_mfma_f32_32x32x16_bf16(a1, b1, acc[1][1], 0, 0, 0);
  }
  __syncthreads();  // everyone done reading ldsA

  // ---- bias + silu -> H2 bf16 back into ldsA (swizzled [row][k]) ----
  {
    const float b2v0 = b2[wn * 64 + c];
    const float b2v1 = b2[wn * 64 + 32 + c];
    #pragma unroll
    for (int m = 0; m < 2; ++m) {
      #pragma unroll
      for (int n = 0; n < 2; ++n) {
        const int cg = wn * 64 + n * 32 + c;
        const float bias = n ? b2v1 : b2v0;
        #pragma unroll
        for (int r = 0; r < 16; ++r) {
          const int rloc = (r & 3) + 8 * (r >> 2) + 4 * hi;
          const int row  = wm * 64 + m * 32 + rloc;
          const unsigned short hv = bf16u(silu_f(acc[m][n][r] + bias));
          *(unsigned short*)((char*)ldsA + ((row * 256 + cg * 2) ^ ((row & 7) << 4))) = hv;
        }
      }
    }
  }
  __syncthreads();

  // ---- GEMM2: H2 (128x128) @ W3 (128x16) -> out, 16x16x32 bf16 MFMA ----
  const int l16 = lane & 15, l4 = lane >> 4;
  short8 w3r[4];
  #pragma unroll
  for (int ks = 0; ks < 4; ++ks)
    w3r[ks] = *(const short8*)(w3f + (ks * 64 + lane) * 8);

  f32x4 acc2[2] = {};
  #pragma unroll
  for (int ks = 0; ks < 4; ++ks) {
    const int kb2 = (ks * 32 + l4 * 8) * 2;
    #pragma unroll
    for (int m = 0; m < 2; ++m) {
      const int row = wid * 32 + m * 16 + l16;
      short8 af = *(const short8*)((const char*)ldsA + ((row * 256 + kb2) ^ ((row & 7) << 4)));
      acc2[m] = __builtin_amdgcn_mfma_f32_16x16x32_bf16(af, w3r[ks], acc2[m], 0, 0, 0);
    }
  }

  const float b3v = b3[l16];
  #pragma unroll
  for (int m = 0; m < 2; ++m) {
    const int rbase = r0 + wid * 32 + m * 16 + l4 * 4;
    #pragma unroll
    for (int j = 0; j < 4; ++j) {
      out[(rbase + j) * 16 + l16] = acc2[m][j] + b3v;
    }
  }
}

extern "C" void kernel_launch(void* const* d_in, const int* in_sizes, int n_in,
                              void* d_out, int out_size, void* d_ws, size_t ws_size,
                              hipStream_t stream) {
  const int*   z_j    = (const int*)d_in[0];
  const int*   z_k    = (const int*)d_in[1];
  const float* e_feat = (const float*)d_in[2];
  const float* z_emb  = (const float*)d_in[3];
  const float* W1     = (const float*)d_in[4];
  const float* b1     = (const float*)d_in[5];
  const float* W2     = (const float*)d_in[6];
  const float* b2     = (const float*)d_in[7];
  const float* W3     = (const float*)d_in[8];
  const float* b3     = (const float*)d_in[9];
  float* out = (float*)d_out;
  char*  ws  = (char*)d_ws;

  float*          hp  = (float*)(ws);                  // 2048*128*4 = 1 MB
  float*          he  = (float*)(ws + (1 << 20));      // 400*128*4  = 200 KB
  unsigned short* w2t = (unsigned short*)(ws + 0x140000); // 32 KB
  unsigned short* w3f = (unsigned short*)(ws + 0x148000); // 4 KB

  hipLaunchKernelGGL(prep_emb, dim3(BPn + NEn), dim3(128), 0, stream,
                     z_j, z_k, e_feat, z_emb, W1, b1, hp, he);
  hipLaunchKernelGGL(prep_w, dim3(64), dim3(256), 0, stream, W2, W3, w2t, w3f);
  hipLaunchKernelGGL(fused_main, dim3(RTOT / TILE_R), dim3(256), 0, stream,
                     hp, he, w2t, w3f, b2, b3, out);
}

// Round 2
// 111.635 us; speedup vs baseline: 1.2740x; 1.2740x over previous
//
#include <hip/hip_runtime.h>
#include <hip/hip_bf16.h>

// Problem constants
#define BPn   2048      // B*P
#define NEn   400
#define RTOT  (BPn*NEn) // 819200
#define TILE_R 128

typedef __attribute__((ext_vector_type(8)))  short  short8;
typedef __attribute__((ext_vector_type(4)))  short  short4v;
typedef __attribute__((ext_vector_type(16))) float  f32x16;
typedef __attribute__((ext_vector_type(4)))  float  f32x4;

__device__ __forceinline__ unsigned short bf16c(float x) {
  return __builtin_bit_cast(unsigned short, __float2bfloat16(x));
}

// x * rcp(1+exp(-x)): 5 VALU ops (2 transcendental). Avoids the IEEE div sequence.
__device__ __forceinline__ float silu_f(float x) {
  return x * __builtin_amdgcn_rcpf(1.0f + __expf(-x));
}

// ---------------- prep: hp[2048][128] and he[400][128] (f32) ----------------
__global__ void prep_emb(const int* __restrict__ z_j, const int* __restrict__ z_k,
                         const float* __restrict__ e_feat, const float* __restrict__ z_emb,
                         const float* __restrict__ W1, const float* __restrict__ b1,
                         float* __restrict__ hp, float* __restrict__ he)
{
  const int t = threadIdx.x;           // 0..127
  const int bidx = blockIdx.x;
  if (bidx < BPn) {
    const int zj = z_j[bidx], zk = z_k[bidx];
    const float* ej = z_emb + zj * 64;
    const float* ek = z_emb + zk * 64;
    float acc = b1[t];
    #pragma unroll 8
    for (int k = 0; k < 64; ++k) acc += ej[k] * W1[k * 128 + t];
    #pragma unroll 8
    for (int k = 0; k < 64; ++k) acc += ek[k] * W1[(64 + k) * 128 + t];
    hp[bidx * 128 + t] = acc;
  } else {
    const int e = bidx - BPn;          // 0..399
    float acc = 0.0f;
    #pragma unroll 8
    for (int k = 0; k < 32; ++k) acc += e_feat[e * 32 + k] * W1[(128 + k) * 128 + t];
    he[e * 128 + t] = acc;
  }
}

// ---------------- prep: weights to bf16 ----------------
// w2cm[n][k] = bf16(W2[k][n])  (col-major, unswizzled, read via L1 in GEMM1)
// w3f layout: [ks][lane][j] with B[k=ks*32+(lane>>4)*8+j][col=lane&15]
__global__ void prep_w(const float* __restrict__ W2, const float* __restrict__ W3,
                       unsigned short* __restrict__ w2cm, unsigned short* __restrict__ w3f)
{
  const int idx = blockIdx.x * 256 + threadIdx.x;
  if (idx < 16384) {
    const int n = idx >> 7, k = idx & 127;
    w2cm[idx] = bf16c(W2[k * 128 + n]);
  }
  if (idx < 2048) {
    const int ks = idx >> 9;
    const int l  = (idx >> 3) & 63;
    const int j  = idx & 7;
    const int k  = ks * 32 + ((l >> 4) & 3) * 8 + j;
    const int col = l & 15;
    w3f[idx] = bf16c(W3[k * 16 + col]);
  }
}

// ---------------- fused main ----------------
__global__ __launch_bounds__(256, 4)
void fused_main(const float* __restrict__ hp, const float* __restrict__ he,
                const unsigned short* __restrict__ w2cm, const unsigned short* __restrict__ w3f,
                const float* __restrict__ b2, const float* __restrict__ b3,
                float* __restrict__ out)
{
  __shared__ __align__(16) unsigned short ldsA[16384]; // 32KB: A (silu layer1), then H2
  const int t    = threadIdx.x;
  const int lane = t & 63;
  const int wid  = t >> 6;
  const int r0   = blockIdx.x * TILE_R;

  // ---- build A = bf16(silu(hp + he)) into ldsA, swizzled [row][k], swz=(row&15)<<4 ----
  {
    const int row0 = t >> 4;              // 0..15 (constant per thread)
    const int k8   = (t & 15) << 3;       // 0,8,...,120 (constant per thread)
    const int swz  = row0 << 4;           // (row&15)<<4, row&15 == row0 for all i
    #pragma unroll
    for (int i = 0; i < 8; ++i) {
      const int row = row0 + i * 16;
      const int rg  = r0 + row;
      const unsigned int bp = (unsigned int)(((unsigned long long)rg * 2748779070ull) >> 40); // rg/400 exact
      const unsigned int e  = (unsigned int)rg - bp * 400u;
      const float4* hpv = (const float4*)(hp + bp * 128 + k8);
      const float4* hev = (const float4*)(he + e  * 128 + k8);
      const float4 h0 = hpv[0], h1 = hpv[1];
      const float4 g0 = hev[0], g1 = hev[1];
      float v[8] = { h0.x + g0.x, h0.y + g0.y, h0.z + g0.z, h0.w + g0.w,
                     h1.x + g1.x, h1.y + g1.y, h1.z + g1.z, h1.w + g1.w };
      short8 av;
      #pragma unroll
      for (int j = 0; j < 8; ++j) av[j] = (short)bf16c(silu_f(v[j]));
      *(short8*)((char*)ldsA + ((row * 256 + k8 * 2) ^ swz)) = av;
    }
  }
  __syncthreads();

  // ---- GEMM1: swapped operands -> acc = H2pre^T fragments ----
  // acc[m][n]: lane&31 = A-row-local (group m), reg=(r&3)+8*(r>>2)+4*hi = W2-col-local (group n)
  const int wm = wid >> 1, wn = wid & 1;   // 2x2 wave grid, 64x64 wave tile
  const int c  = lane & 31, hi = lane >> 5;
  f32x16 acc[2][2] = {};

  const int rowA = wm * 64 + c;
  const int swzA = (c & 15) << 4;          // (rowA&15)<<4; same for rowA+32
  const unsigned short* w2p0 = w2cm + (wn * 64 + c) * 128 + hi * 8;
  const unsigned short* w2p1 = w2p0 + 32 * 128;
  #pragma unroll
  for (int ks = 0; ks < 8; ++ks) {
    const int kb2 = (ks * 16 + hi * 8) * 2;
    short8 a0 = *(const short8*)((const char*)ldsA + (( rowA       * 256 + kb2) ^ swzA));
    short8 a1 = *(const short8*)((const char*)ldsA + (((rowA + 32) * 256 + kb2) ^ swzA));
    short8 b0 = *(const short8*)(w2p0 + ks * 16);
    short8 b1 = *(const short8*)(w2p1 + ks * 16);
    acc[0][0] = __builtin_amdgcn_mfma_f32_32x32x16_bf16(b0, a0, acc[0][0], 0, 0, 0);
    acc[0][1] = __builtin_amdgcn_mfma_f32_32x32x16_bf16(b1, a0, acc[0][1], 0, 0, 0);
    acc[1][0] = __builtin_amdgcn_mfma_f32_32x32x16_bf16(b0, a1, acc[1][0], 0, 0, 0);
    acc[1][1] = __builtin_amdgcn_mfma_f32_32x32x16_bf16(b1, a1, acc[1][1], 0, 0, 0);
  }
  __syncthreads();  // everyone done reading ldsA (phase A)

  // ---- bias + silu -> H2 bf16 back into ldsA; lane owns a row, reg-quad = 4 consecutive cols ----
  {
    const int swzH = (c & 15) << 4;        // (rowH&15)<<4; m*32 doesn't affect &15
    #pragma unroll
    for (int m = 0; m < 2; ++m) {
      char* rbase = (char*)ldsA + (wm * 64 + m * 32 + c) * 256;
      #pragma unroll
      for (int n = 0; n < 2; ++n) {
        #pragma unroll
        for (int q = 0; q < 4; ++q) {
          const int colb = wn * 64 + n * 32 + q * 8 + hi * 4;  // cols colb..colb+3
          const float4 bv = *(const float4*)(b2 + colb);
          short4v pk;
          pk[0] = (short)bf16c(silu_f(acc[m][n][q * 4 + 0] + bv.x));
          pk[1] = (short)bf16c(silu_f(acc[m][n][q * 4 + 1] + bv.y));
          pk[2] = (short)bf16c(silu_f(acc[m][n][q * 4 + 2] + bv.z));
          pk[3] = (short)bf16c(silu_f(acc[m][n][q * 4 + 3] + bv.w));
          *(short4v*)(rbase + ((colb * 2) ^ swzH)) = pk;
        }
      }
    }
  }
  __syncthreads();

  // ---- GEMM2: H2 (128x128) @ W3 (128x16) -> out, 16x16x32 bf16 MFMA ----
  const int l16 = lane & 15, l4 = lane >> 4;
  short8 w3r[4];
  #pragma unroll
  for (int ks = 0; ks < 4; ++ks)
    w3r[ks] = *(const short8*)(w3f + (ks * 64 + lane) * 8);

  const int swz2 = l16 << 4;               // (row&15)<<4 == l16<<4
  f32x4 acc2[2] = {};
  #pragma unroll
  for (int ks = 0; ks < 4; ++ks) {
    const int kb2 = ks * 64 + l4 * 16;     // byte offset of k-slice
    #pragma unroll
    for (int m = 0; m < 2; ++m) {
      const int row = wid * 32 + m * 16 + l16;
      short8 af = *(const short8*)((const char*)ldsA + ((row * 256 + kb2) ^ swz2));
      acc2[m] = __builtin_amdgcn_mfma_f32_16x16x32_bf16(af, w3r[ks], acc2[m], 0, 0, 0);
    }
  }

  const float b3v = b3[l16];
  #pragma unroll
  for (int m = 0; m < 2; ++m) {
    const int rbase = r0 + wid * 32 + m * 16 + l4 * 4;
    #pragma unroll
    for (int j = 0; j < 4; ++j) {
      out[(rbase + j) * 16 + l16] = acc2[m][j] + b3v;
    }
  }
}

extern "C" void kernel_launch(void* const* d_in, const int* in_sizes, int n_in,
                              void* d_out, int out_size, void* d_ws, size_t ws_size,
                              hipStream_t stream) {
  const int*   z_j    = (const int*)d_in[0];
  const int*   z_k    = (const int*)d_in[1];
  const float* e_feat = (const float*)d_in[2];
  const float* z_emb  = (const float*)d_in[3];
  const float* W1     = (const float*)d_in[4];
  const float* b1     = (const float*)d_in[5];
  const float* W2     = (const float*)d_in[6];
  const float* b2     = (const float*)d_in[7];
  const float* W3     = (const float*)d_in[8];
  const float* b3     = (const float*)d_in[9];
  float* out = (float*)d_out;
  char*  ws  = (char*)d_ws;

  float*          hp   = (float*)(ws);                   // 2048*128*4 = 1 MB
  float*          he   = (float*)(ws + (1 << 20));       // 400*128*4  = 200 KB
  unsigned short* w2cm = (unsigned short*)(ws + 0x140000); // 32 KB
  unsigned short* w3f  = (unsigned short*)(ws + 0x148000); // 4 KB

  hipLaunchKernelGGL(prep_emb, dim3(BPn + NEn), dim3(128), 0, stream,
                     z_j, z_k, e_feat, z_emb, W1, b1, hp, he);
  hipLaunchKernelGGL(prep_w, dim3(64), dim3(256), 0, stream, W2, W3, w2cm, w3f);
  hipLaunchKernelGGL(fused_main, dim3(RTOT / TILE_R), dim3(256), 0, stream,
                     hp, he, w2cm, w3f, b2, b3, out);
}